// Round 6
// baseline (46.441 us; speedup 1.0000x reference)
//
#include <hip/hip_runtime.h>

#define L_COLS 2048

typedef float vf4 __attribute__((ext_vector_type(4)));

__device__ __forceinline__ float wave_red(float v) {
#pragma unroll
    for (int m = 32; m >= 1; m >>= 1) v += __shfl_xor(v, m, 64);
    return v;
}

// ---------------------------------------------------------------------------
// Init: one wave computes slice bounds from ppm (register min/max + shfl) and
// zeroes the accumulators.
// Python: start = min(where(ppm <= hi)), stop = max(where(ppm >= lo)); [start:stop)
// windows: gaba(2.8,3.2), glx_shape(3.6,3.9), glx_range(3.55,3.95)
// ---------------------------------------------------------------------------
__global__ __launch_bounds__(64) void init_kernel(const float* __restrict__ ppm,
                                                  float* __restrict__ acc,
                                                  int* __restrict__ ob) {
    const int lane = threadIdx.x;
    if (lane < 4) acc[lane] = 0.f;

    int mn0 = 0x7fffffff, mn1 = 0x7fffffff, mn2 = 0x7fffffff;
    int mx0 = -1, mx1 = -1, mx2 = -1;
    const vf4* __restrict__ p4 = (const vf4*)ppm;
#pragma unroll
    for (int k = 0; k < L_COLS / 256; ++k) {
        const int j = k * 64 + lane;
        const vf4 pv = p4[j];
        const float ps[4] = {pv.x, pv.y, pv.z, pv.w};
#pragma unroll
        for (int e = 0; e < 4; ++e) {
            const int c = 4 * j + e;
            const float p = ps[e];
            if (p <= 3.2f)  mn0 = min(mn0, c);
            if (p >= 2.8f)  mx0 = max(mx0, c);
            if (p <= 3.9f)  mn1 = min(mn1, c);
            if (p >= 3.6f)  mx1 = max(mx1, c);
            if (p <= 3.95f) mn2 = min(mn2, c);
            if (p >= 3.55f) mx2 = max(mx2, c);
        }
    }
#pragma unroll
    for (int m = 32; m >= 1; m >>= 1) {
        mn0 = min(mn0, __shfl_xor(mn0, m, 64));
        mx0 = max(mx0, __shfl_xor(mx0, m, 64));
        mn1 = min(mn1, __shfl_xor(mn1, m, 64));
        mx1 = max(mx1, __shfl_xor(mx1, m, 64));
        mn2 = min(mn2, __shfl_xor(mn2, m, 64));
        mx2 = max(mx2, __shfl_xor(mx2, m, 64));
    }
    if (lane == 0) {
        ob[0] = mn0; ob[1] = mx0;   // gaba  [lo:hi)
        ob[2] = mn1; ob[3] = mx1;   // glx shape
        ob[4] = mn2; ob[5] = mx2;   // glx range
    }
}

// ---------------------------------------------------------------------------
// One wave per row. Issue ALL 16 row loads, then sched_barrier(0) so the
// scheduler cannot sink loads into the consume loop (Round-4 failure mode:
// VGPR=48 proved staging was undone -> ~3KB/wave in flight -> latency-bound).
// With 16 KB/wave genuinely outstanding, per-CU in-flight bytes exceed the
// ~10 KB Little's-law requirement for HBM saturation.
// Pearson via raw moments (norm01 is positive-affine -> invariant).
// acc[0]=Σ(0.6*r_gaba+0.4*r_glx), acc[1]=Σ|d| gaba, acc[2]=Σ|d| glx_range,
// acc[3]=Σ|d| global
// ---------------------------------------------------------------------------
__global__ __launch_bounds__(256, 2) void loss_main(const float* __restrict__ x,
                                                    const float* __restrict__ y,
                                                    const int* __restrict__ ob,
                                                    float* __restrict__ acc) {
    const int lane = threadIdx.x & 63;
    const int wv   = threadIdx.x >> 6;
    const long row = (long)blockIdx.x * 4 + wv;

    const int g_lo = ob[0], g_hi = ob[1];
    const int s_lo = ob[2], s_hi = ob[3];
    const int r_lo = ob[4], r_hi = ob[5];
    const int lo_any = min(min(g_lo, s_lo), r_lo);
    const int hi_any = max(max(g_hi, s_hi), r_hi);

    const vf4* __restrict__ x4 = (const vf4*)(x + row * L_COLS);
    const vf4* __restrict__ y4 = (const vf4*)(y + row * L_COLS);

    // ---- stage full row pair; interleaved x/y so chunk k's data arrives in
    // issue order (first consume waits at vmcnt(14), compute overlaps returns)
    vf4 xr[8], yr[8];
#pragma unroll
    for (int k = 0; k < 8; ++k) {
        xr[k] = x4[k * 64 + lane];
        yr[k] = y4[k * 64 + lane];
    }
    __builtin_amdgcn_sched_barrier(0);   // nothing moves across: loads stay clustered

    float gl = 0.f;
    float a_sx = 0, a_sy = 0, a_xy = 0, a_xx = 0, a_yy = 0, a_mae = 0;
    float b_sx = 0, b_sy = 0, b_xy = 0, b_xx = 0, b_yy = 0;
    float r_mae = 0;

#pragma unroll
    for (int k = 0; k < 8; ++k) {
        const vf4 xv = xr[k];
        const vf4 yv = yr[k];
        const float d0 = fabsf(xv.x - yv.x), d1 = fabsf(xv.y - yv.y);
        const float d2 = fabsf(xv.z - yv.z), d3 = fabsf(xv.w - yv.w);
        gl += (d0 + d1) + (d2 + d3);

        // wave-uniform: can this 256-col chunk touch any window?
        if (k * 256 < hi_any && k * 256 + 256 > lo_any) {
            const float xs[4] = {xv.x, xv.y, xv.z, xv.w};
            const float ys[4] = {yv.x, yv.y, yv.z, yv.w};
            const float ds[4] = {d0, d1, d2, d3};
#pragma unroll
            for (int e = 0; e < 4; ++e) {
                const int c = k * 256 + 4 * lane + e;
                const float xe = xs[e], ye = ys[e];
                if (c >= g_lo && c < g_hi) {
                    a_sx += xe; a_sy += ye; a_xy += xe * ye;
                    a_xx += xe * xe; a_yy += ye * ye; a_mae += ds[e];
                }
                if (c >= s_lo && c < s_hi) {
                    b_sx += xe; b_sy += ye; b_xy += xe * ye;
                    b_xx += xe * xe; b_yy += ye * ye;
                }
                if (c >= r_lo && c < r_hi) r_mae += ds[e];
            }
        }
    }

    gl    = wave_red(gl);
    a_sx  = wave_red(a_sx);  a_sy = wave_red(a_sy);
    a_xy  = wave_red(a_xy);  a_xx = wave_red(a_xx);  a_yy = wave_red(a_yy);
    a_mae = wave_red(a_mae);
    b_sx  = wave_red(b_sx);  b_sy = wave_red(b_sy);
    b_xy  = wave_red(b_xy);  b_xx = wave_red(b_xx);  b_yy = wave_red(b_yy);
    r_mae = wave_red(r_mae);

    __shared__ float part[4][4];
    if (lane == 0) {
        const float ng = (float)(g_hi - g_lo);
        const float ns = (float)(s_hi - s_lo);
        const float covA = a_xy - a_sx * a_sy / ng;
        const float vAx  = a_xx - a_sx * a_sx / ng;
        const float vAy  = a_yy - a_sy * a_sy / ng;
        const float scoreA = covA * rsqrtf(vAx * vAy);
        const float covB = b_xy - b_sx * b_sy / ns;
        const float vBx  = b_xx - b_sx * b_sx / ns;
        const float vBy  = b_yy - b_sy * b_sy / ns;
        const float scoreB = covB * rsqrtf(vBx * vBy);
        part[wv][0] = 0.6f * scoreA + 0.4f * scoreB;
        part[wv][1] = a_mae;
        part[wv][2] = r_mae;
        part[wv][3] = gl;
    }
    __syncthreads();
    if (threadIdx.x < 4) {
        const float s = part[0][threadIdx.x] + part[1][threadIdx.x] +
                        part[2][threadIdx.x] + part[3][threadIdx.x];
        atomicAdd(&acc[threadIdx.x], s);
    }
}

// ---------------------------------------------------------------------------
// Finalize: single thread combines partial sums into the scalar loss.
// ---------------------------------------------------------------------------
__global__ void finalize_kernel(const float* __restrict__ acc, const int* __restrict__ ob,
                                int Brows, float* __restrict__ out) {
    const float ng = (float)(ob[1] - ob[0]);
    const float nr = (float)(ob[5] - ob[4]);
    const float Bf = (float)Brows;
    const float shape_loss = 1.f - acc[0] / Bf;
    const float gaba_mae = acc[1] / (Bf * ng);
    const float glx_mae  = acc[2] / (Bf * nr);
    const float glob_mae = acc[3] / (Bf * (float)L_COLS);
    const float range_loss = (gaba_mae * 6.f + glx_mae * 3.f + glob_mae) * 0.1f;
    out[0] = shape_loss + range_loss * 0.5f;
}

extern "C" void kernel_launch(void* const* d_in, const int* in_sizes, int n_in,
                              void* d_out, int out_size, void* d_ws, size_t ws_size,
                              hipStream_t stream) {
    const float* x   = (const float*)d_in[0];
    const float* ppm = (const float*)d_in[1];
    const float* y   = (const float*)d_in[2];
    const int L = in_sizes[1];          // 2048 (== L_COLS)
    const int Brows = in_sizes[0] / L;  // 8192

    float* acc = (float*)d_ws;                 // 4 floats of accumulators
    int*   ob  = (int*)((char*)d_ws + 64);     // 6 ints of bounds

    init_kernel<<<1, 64, 0, stream>>>(ppm, acc, ob);
    loss_main<<<Brows / 4, 256, 0, stream>>>(x, y, ob, acc);
    finalize_kernel<<<1, 1, 0, stream>>>(acc, ob, Brows, (float*)d_out);
}